// Round 11
// baseline (1522.892 us; speedup 1.0000x reference)
//
#include <hip/hip_runtime.h>
#include <hip/hip_bf16.h>
#include <stdint.h>

typedef __attribute__((ext_vector_type(4))) float f32x4;
typedef __attribute__((ext_vector_type(8))) short bf16x8;
typedef __attribute__((ext_vector_type(4))) float float4v;

static constexpr int KD    = 1024;   // hidden dim
static constexpr int ND    = 2048;   // expert out dim (gate+up)
static constexpr int NE    = 8;      // experts
static constexpr int MROWS = 16384;  // hidden rows
static constexpr int RFLAT = 32768;  // M * topk
static constexpr int OUTN  = 1024;   // output cols (ND/2)

// ws ints: cnt[8]@0, cursor[8]@8, offs[9]@16, mode@31, tileoff[9]@40
static constexpr size_t WS_ROWLIST = 1024;
static constexpr size_t WS_HB      = 262144;
static constexpr size_t WS_WT      = 262144 + (size_t)33554432;

__device__ __forceinline__ unsigned short f2bf(float f) {
  uint32_t u = __float_as_uint(f);
  uint32_t r = (u + 0x7FFFu + ((u >> 16) & 1u)) >> 16;
  return (unsigned short)r;
}

__device__ __forceinline__ void gload16(const void* g, void* l) {
  __builtin_amdgcn_global_load_lds(
      (__attribute__((address_space(1))) void*)(void*)g,
      (__attribute__((address_space(3))) void*)l, 16, 0, 0);
}

// Detect int32-converted vs raw-int64 ids (odd 32-bit slots all zero => int64).
__global__ void k_detect(const int* __restrict__ ids32, int* __restrict__ wsi) {
  int t = blockIdx.x * 256 + threadIdx.x;
  int i = 2 * t + 1;
  if (i < RFLAT && ids32[i] != 0) atomicOr(&wsi[31], 1);
}

__device__ __forceinline__ int read_id(const int* ids32, int t, int mode) {
  return (mode ? ids32[t] : ids32[2 * t]) & 7;
}

// LDS-histogram count.
__global__ void k_count(const int* __restrict__ ids, int* __restrict__ wsi) {
  __shared__ int h[8];
  const int tid = threadIdx.x;
  if (tid < 8) h[tid] = 0;
  __syncthreads();
  const int mode = wsi[31];
  const int base = blockIdx.x * 512 + tid;
  atomicAdd(&h[read_id(ids, base, mode)], 1);
  atomicAdd(&h[read_id(ids, base + 256, mode)], 1);
  __syncthreads();
  if (tid < 8 && h[tid]) atomicAdd(&wsi[tid], h[tid]);
}

__global__ void k_scan(int* wsi) {
  if (threadIdx.x == 0) {
    int o = 0, to = 0;
    for (int e = 0; e < NE; ++e) {
      int c = wsi[e];
      wsi[16 + e] = o;   // offs
      wsi[8 + e]  = o;   // cursor
      wsi[40 + e] = to;  // tile offset (256-row tiles)
      o += c;
      to += (c + 255) / 256;
    }
    wsi[16 + NE] = o;
    wsi[40 + NE] = to;
  }
}

// LDS-histogram scatter: per-block base + local rank.
__global__ void k_scatter(const int* __restrict__ ids, int* __restrict__ wsi,
                          int* __restrict__ rowlist) {
  __shared__ int h[8], base[8], c2[8];
  const int tid = threadIdx.x;
  if (tid < 8) { h[tid] = 0; c2[tid] = 0; }
  __syncthreads();
  const int mode = wsi[31];
  const int t = blockIdx.x * 256 + tid;
  const int e = read_id(ids, t, mode);
  atomicAdd(&h[e], 1);
  __syncthreads();
  if (tid < 8 && h[tid]) base[tid] = atomicAdd(&wsi[8 + tid], h[tid]);
  __syncthreads();
  const int r = atomicAdd(&c2[e], 1);
  rowlist[base[e] + r] = t;
}

__global__ void k_cvtH(const float* __restrict__ H, unsigned short* __restrict__ Hb) {
  const int n4 = (MROWS * KD) / 4;
  const int stride = gridDim.x * blockDim.x;
  for (int i = blockIdx.x * blockDim.x + threadIdx.x; i < n4; i += stride) {
    float4v v = ((const float4v*)H)[i];
    ushort4 o;
    o.x = f2bf(v.x); o.y = f2bf(v.y); o.z = f2bf(v.z); o.w = f2bf(v.w);
    ((ushort4*)Hb)[i] = o;
  }
}

// Transpose + convert: W[e][k][n] fp32 -> Wt[e][n][k] bf16 (64x64 tiles,
// 16B vectorized stores).
__global__ void k_cvtW(const float* __restrict__ W, unsigned short* __restrict__ Wt) {
  __shared__ float tile[64][65];
  const int e  = blockIdx.z;
  const int n0 = blockIdx.x * 64;
  const int k0 = blockIdx.y * 64;
  const int t  = threadIdx.x;          // 512
  const int tx = t & 63, ty = t >> 6;  // load phase: 64 x 8
  const float* Wp = W + (size_t)e * KD * ND;
  #pragma unroll
  for (int i = ty; i < 64; i += 8)
    tile[i][tx] = Wp[(size_t)(k0 + i) * ND + n0 + tx];
  __syncthreads();
  // store phase: thread -> n = t>>3, k-chunk = (t&7)*8; one 16B store
  const int n = t >> 3, kc8 = (t & 7) * 8;
  ushort4 o0, o1;
  o0.x = f2bf(tile[kc8 + 0][n]); o0.y = f2bf(tile[kc8 + 1][n]);
  o0.z = f2bf(tile[kc8 + 2][n]); o0.w = f2bf(tile[kc8 + 3][n]);
  o1.x = f2bf(tile[kc8 + 4][n]); o1.y = f2bf(tile[kc8 + 5][n]);
  o1.z = f2bf(tile[kc8 + 6][n]); o1.w = f2bf(tile[kc8 + 7][n]);
  unsigned short* Wo = Wt + (size_t)e * ND * KD + (size_t)(n0 + n) * KD + k0 + kc8;
  *(ushort4*)Wo = o0;
  *(ushort4*)(Wo + 4) = o1;
}

// Grouped GEMM: BK=32 double-buffer, 2 blocks/CU (16 waves, 4/SIMD).
// 256 rows x 256 wcols, 32 K-steps, 512 threads = 8 waves (2M x 4N),
// wave tile 128x64, acc[8][4], 16x16x32 MFMA.
// LDS: 2 slots x 32KB (A[256]x64B @0, B[256]x64B @16K) + s_rows = 65KB
// -> 2 co-resident blocks per CU; sibling-block waves hide the per-step
// vmcnt(0) drain and fill the bursty LDS pipe (m114 cross-wave overlap).
// Per K-step: stage next slot (4 gloads) ; 12 ds_read_b128 ; 32 MFMA
// (setprio) ; vmcnt(0) ; ONE barrier. 32 barriers total (vs 128 in R9).
// Swizzle: chunk slot s of row r holds global chunk s ^ ((r>>1)&3) ->
// conflict-free b128 reads; linear gload dest + pre-swizzled src (rule 21).
__global__ __launch_bounds__(512, 4) void k_gemm(
    const unsigned short* __restrict__ Hb, const unsigned short* __restrict__ Wt,
    const int* __restrict__ wsi, const int* __restrict__ rowlist,
    float* __restrict__ Out) {
  const int bid = blockIdx.x;
  const int xcd = bid & 7;
  const int j   = bid >> 3;
  const int colblk = j & 7;        // col-blocks fastest within an XCD
  const int rt  = xcd + (j >> 3) * 8;
  if (rt >= wsi[48]) return;
  int e = 0;
  #pragma unroll
  for (int q = 1; q < 8; ++q)
    if (rt >= wsi[40 + q]) e = q;
  const int cnt = wsi[e];
  const int tile_base = (rt - wsi[40 + e]) * 256;
  const int tile_cnt = min(256, cnt - tile_base);
  const int off = wsi[16 + e] + tile_base;
  const int c0 = colblk * 128;     // out-col base

  constexpr int SLOT = 32768;
  __shared__ char lds[2 * SLOT];
  __shared__ int s_rows[256];

  const int t = threadIdx.x;
  if (t < 256) s_rows[t] = rowlist[off + min(t, tile_cnt - 1)];
  __syncthreads();

  // Staging: thread t covers rows/cols (t>>2) and 128+(t>>2), slot chunk t&3.
  // Source chunk = (t&3) ^ ((t>>3)&3) pre-applies read swizzle sigma(r)=(r>>1)&3.
  const int srow = t >> 2;
  const int coff = ((t & 3) ^ ((t >> 3) & 3)) * 16;
  const char* sA0 = (const char*)Hb + (size_t)(s_rows[srow] >> 1) * (KD * 2) + coff;
  const char* sA1 = (const char*)Hb + (size_t)(s_rows[128 + srow] >> 1) * (KD * 2) + coff;
  auto wcol_of = [&](int jc) {
    const int wn_s = jc >> 6, r64 = jc & 63;
    const int h_s = r64 >> 4, l_s = r64 & 15;
    return (h_s < 2) ? (c0 + wn_s * 32 + h_s * 16 + l_s)
                     : (OUTN + c0 + wn_s * 32 + (h_s - 2) * 16 + l_s);
  };
  const char* sB0 = (const char*)Wt + ((size_t)e * ND + wcol_of(srow)) * (KD * 2) + coff;
  const char* sB1 = (const char*)Wt + ((size_t)e * ND + wcol_of(128 + srow)) * (KD * 2) + coff;

  const int lane = t & 63, wid = t >> 6;
  const int wm = wid >> 2, wn = wid & 3;
  const int kc = lane >> 4, l15 = lane & 15;

  f32x4 acc[8][4];
  #pragma unroll
  for (int m = 0; m < 8; ++m)
    #pragma unroll
    for (int h = 0; h < 4; ++h)
      acc[m][h] = (f32x4){0.f, 0.f, 0.f, 0.f};

  // Slot-relative ds_read offsets: A row r @ r*64, B col j @ 16K + j*64,
  // chunk = kc ^ ((row>>1)&3).
  int aoff[8], boff[4];
  #pragma unroll
  for (int m = 0; m < 8; ++m) {
    const int r = wm * 128 + m * 16 + l15;
    aoff[m] = r * 64 + ((kc ^ ((r >> 1) & 3)) * 16);
  }
  #pragma unroll
  for (int h = 0; h < 4; ++h) {
    const int jc = wn * 64 + h * 16 + l15;
    boff[h] = 16384 + jc * 64 + ((kc ^ ((jc >> 1) & 3)) * 16);
  }

  auto SAB = [&](int h, char* slot) {   // stage K-step h (64B/row): 4 loads
    const int go = h * 64;
    gload16(sA0 + go, slot + t * 16);
    gload16(sA1 + go, slot + 8192 + t * 16);
    gload16(sB0 + go, slot + 16384 + t * 16);
    gload16(sB1 + go, slot + 24576 + t * 16);
  };

  bf16x8 af[8], bfv[4];
  auto LD = [&](const char* cb) {
    #pragma unroll
    for (int m = 0; m < 8; ++m) af[m] = *(const bf16x8*)(cb + aoff[m]);
    #pragma unroll
    for (int h = 0; h < 4; ++h) bfv[h] = *(const bf16x8*)(cb + boff[h]);
  };
  auto MM = [&]() {
    __builtin_amdgcn_s_setprio(1);
    #pragma unroll
    for (int m = 0; m < 8; ++m)
      #pragma unroll
      for (int h = 0; h < 4; ++h)
        acc[m][h] =
            __builtin_amdgcn_mfma_f32_16x16x32_bf16(af[m], bfv[h], acc[m][h], 0, 0, 0);
    __builtin_amdgcn_s_setprio(0);
  };
#define GUARD0 asm volatile("s_waitcnt vmcnt(0)" ::: "memory")
#define BAR __builtin_amdgcn_s_barrier()

  // Prologue: stage K-step 0 into slot 0.
  SAB(0, lds);
  GUARD0; BAR;

  for (int k = 0; k < 31; ++k) {
    char* cb = lds + (k & 1) * SLOT;
    char* nb = lds + ((k + 1) & 1) * SLOT;
    SAB(k + 1, nb);      // prefetch next K-step (4 gloads in flight)
    LD(cb);              // 12 ds_read_b128 (compiler-scheduled lgkm waits)
    MM();                // 32 MFMA; consumes all reads -> lgkm drained
    GUARD0; BAR;         // next slot ready; WAR safe (one barrier/step)
  }
  LD(lds + SLOT);        // K-step 31 (slot 1), no staging
  MM();
#undef GUARD0
#undef BAR

  // Fused epilogue: gate = acc[m][h], up = acc[m][h+2], h in {0,1}.
  #pragma unroll
  for (int m = 0; m < 8; ++m) {
    const int rbase = wm * 128 + m * 16 + kc * 4;
    #pragma unroll
    for (int i = 0; i < 4; ++i) {
      const int rl = rbase + i;
      if (rl < tile_cnt) {
        const size_t orow = (size_t)s_rows[rl] * OUTN;
        #pragma unroll
        for (int h = 0; h < 2; ++h) {
          float gg = acc[m][h][i];
          float uu = acc[m][h + 2][i];
          float s = gg / (1.0f + __expf(-gg)) * uu;
          Out[orow + c0 + wn * 32 + h * 16 + l15] = s;
        }
      }
    }
  }
}

extern "C" void kernel_launch(void* const* d_in, const int* in_sizes, int n_in,
                              void* d_out, int out_size, void* d_ws, size_t ws_size,
                              hipStream_t stream) {
  const float* H  = (const float*)d_in[0];
  const float* W  = (const float*)d_in[1];
  const int* ids  = (const int*)d_in[2];
  float* Out      = (float*)d_out;
  char* ws        = (char*)d_ws;
  int* wsi        = (int*)ws;
  int* rowlist    = (int*)(ws + WS_ROWLIST);
  unsigned short* Hb = (unsigned short*)(ws + WS_HB);
  unsigned short* Wt = (unsigned short*)(ws + WS_WT);

  hipMemsetAsync(ws, 0, 1024, stream);
  k_detect<<<RFLAT / 2 / 256, 256, 0, stream>>>(ids, wsi);
  k_count<<<RFLAT / 512, 256, 0, stream>>>(ids, wsi);
  k_scan<<<1, 64, 0, stream>>>(wsi);
  k_scatter<<<RFLAT / 256, 256, 0, stream>>>(ids, wsi, rowlist);
  k_cvtH<<<2048, 256, 0, stream>>>(H, Hb);
  k_cvtW<<<dim3(ND / 64, KD / 64, NE), 512, 0, stream>>>(W, Wt);
  // rowtiles (256-row) <= 136: 17 slots/XCD x 8 XCDs x 8 colblocks
  k_gemm<<<8 * 17 * 8, 512, 0, stream>>>(Hb, Wt, wsi, rowlist, Out);
}

// Round 12
// 228.166 us; speedup vs baseline: 6.6745x; 6.6745x over previous
//
#include <hip/hip_runtime.h>
#include <hip/hip_bf16.h>
#include <stdint.h>

typedef __attribute__((ext_vector_type(4))) float f32x4;
typedef __attribute__((ext_vector_type(8))) short bf16x8;
typedef __attribute__((ext_vector_type(4))) float float4v;

static constexpr int KD    = 1024;   // hidden dim
static constexpr int ND    = 2048;   // expert out dim (gate+up)
static constexpr int NE    = 8;      // experts
static constexpr int MROWS = 16384;  // hidden rows
static constexpr int RFLAT = 32768;  // M * topk
static constexpr int OUTN  = 1024;   // output cols (ND/2)

// ws ints: cnt[8]@0, cursor[8]@8, offs[9]@16, mode@31, tileoff[9]@40
static constexpr size_t WS_ROWLIST = 1024;
static constexpr size_t WS_HB      = 262144;
static constexpr size_t WS_WT      = 262144 + (size_t)33554432;

__device__ __forceinline__ unsigned short f2bf(float f) {
  uint32_t u = __float_as_uint(f);
  uint32_t r = (u + 0x7FFFu + ((u >> 16) & 1u)) >> 16;
  return (unsigned short)r;
}

__device__ __forceinline__ void gload16(const void* g, void* l) {
  __builtin_amdgcn_global_load_lds(
      (__attribute__((address_space(1))) void*)(void*)g,
      (__attribute__((address_space(3))) void*)l, 16, 0, 0);
}

// Detect int32-converted vs raw-int64 ids (odd 32-bit slots all zero => int64).
__global__ void k_detect(const int* __restrict__ ids32, int* __restrict__ wsi) {
  int t = blockIdx.x * 256 + threadIdx.x;
  int i = 2 * t + 1;
  if (i < RFLAT && ids32[i] != 0) atomicOr(&wsi[31], 1);
}

__device__ __forceinline__ int read_id(const int* ids32, int t, int mode) {
  return (mode ? ids32[t] : ids32[2 * t]) & 7;
}

// LDS-histogram count.
__global__ void k_count(const int* __restrict__ ids, int* __restrict__ wsi) {
  __shared__ int h[8];
  const int tid = threadIdx.x;
  if (tid < 8) h[tid] = 0;
  __syncthreads();
  const int mode = wsi[31];
  const int base = blockIdx.x * 512 + tid;
  atomicAdd(&h[read_id(ids, base, mode)], 1);
  atomicAdd(&h[read_id(ids, base + 256, mode)], 1);
  __syncthreads();
  if (tid < 8 && h[tid]) atomicAdd(&wsi[tid], h[tid]);
}

__global__ void k_scan(int* wsi) {
  if (threadIdx.x == 0) {
    int o = 0, to = 0;
    for (int e = 0; e < NE; ++e) {
      int c = wsi[e];
      wsi[16 + e] = o;   // offs
      wsi[8 + e]  = o;   // cursor
      wsi[40 + e] = to;  // tile offset (128-row tiles)
      o += c;
      to += (c + 127) / 128;
    }
    wsi[16 + NE] = o;
    wsi[40 + NE] = to;
  }
}

// LDS-histogram scatter: per-block base + local rank.
__global__ void k_scatter(const int* __restrict__ ids, int* __restrict__ wsi,
                          int* __restrict__ rowlist) {
  __shared__ int h[8], base[8], c2[8];
  const int tid = threadIdx.x;
  if (tid < 8) { h[tid] = 0; c2[tid] = 0; }
  __syncthreads();
  const int mode = wsi[31];
  const int t = blockIdx.x * 256 + tid;
  const int e = read_id(ids, t, mode);
  atomicAdd(&h[e], 1);
  __syncthreads();
  if (tid < 8 && h[tid]) base[tid] = atomicAdd(&wsi[8 + tid], h[tid]);
  __syncthreads();
  const int r = atomicAdd(&c2[e], 1);
  rowlist[base[e] + r] = t;
}

__global__ void k_cvtH(const float* __restrict__ H, unsigned short* __restrict__ Hb) {
  const int n4 = (MROWS * KD) / 4;
  const int stride = gridDim.x * blockDim.x;
  for (int i = blockIdx.x * blockDim.x + threadIdx.x; i < n4; i += stride) {
    float4v v = ((const float4v*)H)[i];
    ushort4 o;
    o.x = f2bf(v.x); o.y = f2bf(v.y); o.z = f2bf(v.z); o.w = f2bf(v.w);
    ((ushort4*)Hb)[i] = o;
  }
}

// Transpose + convert: W[e][k][n] fp32 -> Wt[e][n][k] bf16 (64x64 tiles,
// 16B vectorized stores).
__global__ void k_cvtW(const float* __restrict__ W, unsigned short* __restrict__ Wt) {
  __shared__ float tile[64][65];
  const int e  = blockIdx.z;
  const int n0 = blockIdx.x * 64;
  const int k0 = blockIdx.y * 64;
  const int t  = threadIdx.x;          // 512
  const int tx = t & 63, ty = t >> 6;  // load phase: 64 x 8
  const float* Wp = W + (size_t)e * KD * ND;
  #pragma unroll
  for (int i = ty; i < 64; i += 8)
    tile[i][tx] = Wp[(size_t)(k0 + i) * ND + n0 + tx];
  __syncthreads();
  // store phase: thread -> n = t>>3, k-chunk = (t&7)*8; one 16B store
  const int n = t >> 3, kc8 = (t & 7) * 8;
  ushort4 o0, o1;
  o0.x = f2bf(tile[kc8 + 0][n]); o0.y = f2bf(tile[kc8 + 1][n]);
  o0.z = f2bf(tile[kc8 + 2][n]); o0.w = f2bf(tile[kc8 + 3][n]);
  o1.x = f2bf(tile[kc8 + 4][n]); o1.y = f2bf(tile[kc8 + 5][n]);
  o1.z = f2bf(tile[kc8 + 6][n]); o1.w = f2bf(tile[kc8 + 7][n]);
  unsigned short* Wo = Wt + (size_t)e * ND * KD + (size_t)(n0 + n) * KD + k0 + kc8;
  *(ushort4*)Wo = o0;
  *(ushort4*)(Wo + 4) = o1;
}

// Grouped GEMM, m97-class occupancy config: 128 rows x 64 out-cols
// (128 wcols: 64 gate + 64 up), BK=32, 32 K-steps, 256 threads = 4 waves
// (2M x 2N), wave tile 64 rows x 32 out-cols, acc[4][4] = 64 AGPR ->
// total regs ~150 -> 3 waves/SIMD (12 waves/CU, 3 blocks): independent
// blocks overlap MFMA/LDS/VMEM across each other's barriers (m114).
// LDS: 2 slots x 16KB (A[128]x64B @0, B[128]x64B @8K) + s_rows = 32.5KB.
// Per K-step: stage next slot (4 gloads) ; 8 ds_read_b128 ; 16 MFMA ;
// vmcnt(0) ; ONE barrier (drain hidden by sibling blocks).
// Swizzle: chunk slot s of row r holds global chunk s ^ ((r>>1)&3) ->
// conflict-free b128 reads; linear gload dest + pre-swizzled src (rule 21).
__global__ __launch_bounds__(256, 3) void k_gemm(
    const unsigned short* __restrict__ Hb, const unsigned short* __restrict__ Wt,
    const int* __restrict__ wsi, const int* __restrict__ rowlist,
    float* __restrict__ Out) {
  const int bid = blockIdx.x;
  const int xcd = bid & 7;
  const int j   = bid >> 3;
  const int colblk = j & 15;       // col-blocks fastest within an XCD
  const int rt  = xcd + (j >> 4) * 8;
  if (rt >= wsi[48]) return;
  int e = 0;
  #pragma unroll
  for (int q = 1; q < 8; ++q)
    if (rt >= wsi[40 + q]) e = q;
  const int cnt = wsi[e];
  const int tile_base = (rt - wsi[40 + e]) * 128;
  const int tile_cnt = min(128, cnt - tile_base);
  const int off = wsi[16 + e] + tile_base;
  const int c0 = colblk * 64;      // out-col base

  constexpr int SLOT = 16384;
  __shared__ char lds[2 * SLOT];
  __shared__ int s_rows[128];

  const int t = threadIdx.x;
  if (t < 128) s_rows[t] = rowlist[off + min(t, tile_cnt - 1)];
  __syncthreads();

  // Staging: thread t covers rows/cols (t>>2) and 64+(t>>2), slot chunk t&3.
  // Source chunk = (t&3) ^ ((t>>3)&3) pre-applies read swizzle sigma(r)=(r>>1)&3
  // (sigma identical for r and r+64).
  const int srow = t >> 2;
  const int coff = ((t & 3) ^ ((t >> 3) & 3)) * 16;
  const char* sA0 = (const char*)Hb + (size_t)(s_rows[srow] >> 1) * (KD * 2) + coff;
  const char* sA1 = (const char*)Hb + (size_t)(s_rows[64 + srow] >> 1) * (KD * 2) + coff;
  auto wcol_of = [&](int jc) {   // jc in [0,128): LDS B col -> weight col
    const int wn_s = jc >> 6, r64 = jc & 63;
    const int h_s = r64 >> 4, l_s = r64 & 15;
    return (h_s < 2) ? (c0 + wn_s * 32 + h_s * 16 + l_s)
                     : (OUTN + c0 + wn_s * 32 + (h_s - 2) * 16 + l_s);
  };
  const char* sB0 = (const char*)Wt + ((size_t)e * ND + wcol_of(srow)) * (KD * 2) + coff;
  const char* sB1 = (const char*)Wt + ((size_t)e * ND + wcol_of(64 + srow)) * (KD * 2) + coff;

  const int lane = t & 63, wid = t >> 6;
  const int wm = wid >> 1, wn = wid & 1;
  const int kc = lane >> 4, l15 = lane & 15;

  f32x4 acc[4][4];
  #pragma unroll
  for (int m = 0; m < 4; ++m)
    #pragma unroll
    for (int h = 0; h < 4; ++h)
      acc[m][h] = (f32x4){0.f, 0.f, 0.f, 0.f};

  // Slot-relative ds_read offsets: A row r @ r*64, B col j @ 8K + j*64,
  // chunk = kc ^ ((row>>1)&3).
  int aoff[4], boff[4];
  #pragma unroll
  for (int m = 0; m < 4; ++m) {
    const int r = wm * 64 + m * 16 + l15;
    aoff[m] = r * 64 + ((kc ^ ((r >> 1) & 3)) * 16);
  }
  #pragma unroll
  for (int h = 0; h < 4; ++h) {
    const int jc = wn * 64 + h * 16 + l15;
    boff[h] = 8192 + jc * 64 + ((kc ^ ((jc >> 1) & 3)) * 16);
  }

  auto SAB = [&](int h, char* slot) {   // stage K-step h (64B/row): 4 loads
    const int go = h * 64;
    gload16(sA0 + go, slot + t * 16);
    gload16(sA1 + go, slot + 4096 + t * 16);
    gload16(sB0 + go, slot + 8192 + t * 16);
    gload16(sB1 + go, slot + 12288 + t * 16);
  };

  bf16x8 af[4], bfv[4];
  auto LD = [&](const char* cb) {
    #pragma unroll
    for (int m = 0; m < 4; ++m) af[m] = *(const bf16x8*)(cb + aoff[m]);
    #pragma unroll
    for (int h = 0; h < 4; ++h) bfv[h] = *(const bf16x8*)(cb + boff[h]);
  };
  auto MM = [&]() {
    __builtin_amdgcn_s_setprio(1);
    #pragma unroll
    for (int m = 0; m < 4; ++m)
      #pragma unroll
      for (int h = 0; h < 4; ++h)
        acc[m][h] =
            __builtin_amdgcn_mfma_f32_16x16x32_bf16(af[m], bfv[h], acc[m][h], 0, 0, 0);
    __builtin_amdgcn_s_setprio(0);
  };
#define GUARD0 asm volatile("s_waitcnt vmcnt(0)" ::: "memory")
#define BAR __builtin_amdgcn_s_barrier()

  // Prologue: stage K-step 0 into slot 0.
  SAB(0, lds);
  GUARD0; BAR;

  for (int k = 0; k < 31; ++k) {
    char* cb = lds + (k & 1) * SLOT;
    char* nb = lds + ((k + 1) & 1) * SLOT;
    SAB(k + 1, nb);      // prefetch next K-step (4 gloads in flight)
    LD(cb);              // 8 ds_read_b128
    MM();                // 16 MFMA
    GUARD0; BAR;         // drain hidden by 2 sibling blocks on the CU
  }
  LD(lds + SLOT);        // K-step 31 (slot 1), no staging
  MM();
#undef GUARD0
#undef BAR

  // Fused epilogue: gate = acc[m][h], up = acc[m][h+2], h in {0,1}.
  #pragma unroll
  for (int m = 0; m < 4; ++m) {
    const int rbase = wm * 64 + m * 16 + kc * 4;
    #pragma unroll
    for (int i = 0; i < 4; ++i) {
      const int rl = rbase + i;
      if (rl < tile_cnt) {
        const size_t orow = (size_t)s_rows[rl] * OUTN;
        #pragma unroll
        for (int h = 0; h < 2; ++h) {
          float gg = acc[m][h][i];
          float uu = acc[m][h + 2][i];
          float s = gg / (1.0f + __expf(-gg)) * uu;
          Out[orow + c0 + wn * 32 + h * 16 + l15] = s;
        }
      }
    }
  }
}

extern "C" void kernel_launch(void* const* d_in, const int* in_sizes, int n_in,
                              void* d_out, int out_size, void* d_ws, size_t ws_size,
                              hipStream_t stream) {
  const float* H  = (const float*)d_in[0];
  const float* W  = (const float*)d_in[1];
  const int* ids  = (const int*)d_in[2];
  float* Out      = (float*)d_out;
  char* ws        = (char*)d_ws;
  int* wsi        = (int*)ws;
  int* rowlist    = (int*)(ws + WS_ROWLIST);
  unsigned short* Hb = (unsigned short*)(ws + WS_HB);
  unsigned short* Wt = (unsigned short*)(ws + WS_WT);

  hipMemsetAsync(ws, 0, 1024, stream);
  k_detect<<<RFLAT / 2 / 256, 256, 0, stream>>>(ids, wsi);
  k_count<<<RFLAT / 512, 256, 0, stream>>>(ids, wsi);
  k_scan<<<1, 64, 0, stream>>>(wsi);
  k_scatter<<<RFLAT / 256, 256, 0, stream>>>(ids, wsi, rowlist);
  k_cvtH<<<2048, 256, 0, stream>>>(H, Hb);
  k_cvtW<<<dim3(ND / 64, KD / 64, NE), 512, 0, stream>>>(W, Wt);
  // rowtiles (128-row) <= 263: 33 slots/XCD x 8 XCDs x 16 colblocks
  k_gemm<<<8 * 33 * 16, 256, 0, stream>>>(Hb, Wt, wsi, rowlist, Out);
}

// Round 13
// 222.135 us; speedup vs baseline: 6.8557x; 1.0272x over previous
//
#include <hip/hip_runtime.h>
#include <hip/hip_bf16.h>
#include <stdint.h>

typedef __attribute__((ext_vector_type(4))) float f32x4;
typedef __attribute__((ext_vector_type(8))) short bf16x8;
typedef __attribute__((ext_vector_type(4))) float float4v;

static constexpr int KD    = 1024;   // hidden dim
static constexpr int ND    = 2048;   // expert out dim (gate+up)
static constexpr int NE    = 8;      // experts
static constexpr int MROWS = 16384;  // hidden rows
static constexpr int RFLAT = 32768;  // M * topk
static constexpr int OUTN  = 1024;   // output cols (ND/2)

// ws ints: cnt[8]@0, cursor[8]@8, offs[9]@16, tileoff[9]@40
static constexpr size_t WS_ROWLIST = 1024;
static constexpr size_t WS_HB      = 262144;
static constexpr size_t WS_WT      = 262144 + (size_t)33554432;

__device__ __forceinline__ unsigned short f2bf(float f) {
  uint32_t u = __float_as_uint(f);
  uint32_t r = (u + 0x7FFFu + ((u >> 16) & 1u)) >> 16;
  return (unsigned short)r;
}

__device__ __forceinline__ void gload16(const void* g, void* l) {
  __builtin_amdgcn_global_load_lds(
      (__attribute__((address_space(1))) void*)(void*)g,
      (__attribute__((address_space(3))) void*)l, 16, 0, 0);
}

__device__ __forceinline__ int read_id(const int* ids32, int t, int mode) {
  return (mode ? ids32[t] : ids32[2 * t]) & 7;
}

// Local int64-vs-int32 layout detection: probe odd int32 slots of the first
// 512 elements (in-bounds in both layouts). int64 => all zero; genuine int32
// uniform 0..7 has a nonzero among 256 samples with P = 1 - 8^-256.
__device__ __forceinline__ int local_mode(const int* ids, int tid, int* smode) {
  if (tid == 0) *smode = 0;
  __syncthreads();
  if (tid < 256 && ids[2 * tid + 1] != 0) atomicOr(smode, 1);
  __syncthreads();
  return *smode;
}

// LDS-histogram count (mode detected locally).
__global__ void k_count(const int* __restrict__ ids, int* __restrict__ wsi) {
  __shared__ int h[8];
  __shared__ int smode;
  const int tid = threadIdx.x;
  if (tid < 8) h[tid] = 0;
  const int mode = local_mode(ids, tid, &smode);
  const int base = blockIdx.x * 512 + tid;
  atomicAdd(&h[read_id(ids, base, mode)], 1);
  atomicAdd(&h[read_id(ids, base + 256, mode)], 1);
  __syncthreads();
  if (tid < 8 && h[tid]) atomicAdd(&wsi[tid], h[tid]);
}

__global__ void k_scan(int* wsi) {
  if (threadIdx.x == 0) {
    int o = 0, to = 0;
    for (int e = 0; e < NE; ++e) {
      int c = wsi[e];
      wsi[16 + e] = o;   // offs
      wsi[8 + e]  = o;   // cursor
      wsi[40 + e] = to;  // tile offset (128-row tiles)
      o += c;
      to += (c + 127) / 128;
    }
    wsi[16 + NE] = o;
    wsi[40 + NE] = to;
  }
}

// LDS-histogram scatter: per-block base + local rank (mode detected locally).
__global__ void k_scatter(const int* __restrict__ ids, int* __restrict__ wsi,
                          int* __restrict__ rowlist) {
  __shared__ int h[8], base[8], c2[8];
  __shared__ int smode;
  const int tid = threadIdx.x;
  if (tid < 8) { h[tid] = 0; c2[tid] = 0; }
  const int mode = local_mode(ids, tid, &smode);
  const int t = blockIdx.x * 256 + tid;
  const int e = read_id(ids, t, mode);
  atomicAdd(&h[e], 1);
  __syncthreads();
  if (tid < 8 && h[tid]) base[tid] = atomicAdd(&wsi[8 + tid], h[tid]);
  __syncthreads();
  const int r = atomicAdd(&c2[e], 1);
  rowlist[base[e] + r] = t;
}

__global__ void k_cvtH(const float* __restrict__ H, unsigned short* __restrict__ Hb) {
  const int n4 = (MROWS * KD) / 4;
  const int stride = gridDim.x * blockDim.x;
  for (int i = blockIdx.x * blockDim.x + threadIdx.x; i < n4; i += stride) {
    float4v v = ((const float4v*)H)[i];
    ushort4 o;
    o.x = f2bf(v.x); o.y = f2bf(v.y); o.z = f2bf(v.z); o.w = f2bf(v.w);
    ((ushort4*)Hb)[i] = o;
  }
}

// Transpose + convert: W[e][k][n] fp32 -> Wt[e][n][k] bf16 (64x64 tiles,
// 16B vectorized stores).
__global__ void k_cvtW(const float* __restrict__ W, unsigned short* __restrict__ Wt) {
  __shared__ float tile[64][65];
  const int e  = blockIdx.z;
  const int n0 = blockIdx.x * 64;
  const int k0 = blockIdx.y * 64;
  const int t  = threadIdx.x;          // 512
  const int tx = t & 63, ty = t >> 6;  // load phase: 64 x 8
  const float* Wp = W + (size_t)e * KD * ND;
  #pragma unroll
  for (int i = ty; i < 64; i += 8)
    tile[i][tx] = Wp[(size_t)(k0 + i) * ND + n0 + tx];
  __syncthreads();
  const int n = t >> 3, kc8 = (t & 7) * 8;
  ushort4 o0, o1;
  o0.x = f2bf(tile[kc8 + 0][n]); o0.y = f2bf(tile[kc8 + 1][n]);
  o0.z = f2bf(tile[kc8 + 2][n]); o0.w = f2bf(tile[kc8 + 3][n]);
  o1.x = f2bf(tile[kc8 + 4][n]); o1.y = f2bf(tile[kc8 + 5][n]);
  o1.z = f2bf(tile[kc8 + 6][n]); o1.w = f2bf(tile[kc8 + 7][n]);
  unsigned short* Wo = Wt + (size_t)e * ND * KD + (size_t)(n0 + n) * KD + k0 + kc8;
  *(ushort4*)Wo = o0;
  *(ushort4*)(Wo + 4) = o1;
}

// Grouped GEMM: R12 geometry + 3-slot ring + counted vmcnt(4), 3 blocks/CU.
// 128 rows x 64 out-cols (128 wcols), BK=32, 32 K-steps, 256 threads = 4
// waves (2M x 2N), wave tile 64x32-out, acc[4][4], 16x16x32 MFMA.
// LDS: 3 slots x 16KB (A[128]x64B @0, B[128]x64B @8K) + rows = 48.5KB ->
// 3 blocks/CU (12 waves): cross-block overlap hides barrier cost (m114).
// Step k: stage slot(k+2) ; 8 ds_read(slot k) ; 16 MFMA ; vmcnt(4) retires
// step k-1's loads (issued ~2 K-steps earlier) ; ONE barrier. Stage target
// slot(k+2)%3 == slot(k-1): its readers passed step k-1's barrier with
// lgkm drained by their MFMAs -> WAR safe. Never vmcnt(0) until tail.
// Swizzle: chunk slot s of row r holds global chunk s ^ ((r>>1)&3) ->
// conflict-free b128 reads; linear gload dest + pre-swizzled src (rule 21).
__global__ __launch_bounds__(256, 3) void k_gemm(
    const unsigned short* __restrict__ Hb, const unsigned short* __restrict__ Wt,
    const int* __restrict__ wsi, const int* __restrict__ rowlist,
    float* __restrict__ Out) {
  const int bid = blockIdx.x;
  const int xcd = bid & 7;
  const int j   = bid >> 3;
  const int colblk = j & 15;       // col-blocks fastest within an XCD
  const int rt  = xcd + (j >> 4) * 8;
  if (rt >= wsi[48]) return;
  int e = 0;
  #pragma unroll
  for (int q = 1; q < 8; ++q)
    if (rt >= wsi[40 + q]) e = q;
  const int cnt = wsi[e];
  const int tile_base = (rt - wsi[40 + e]) * 128;
  const int tile_cnt = min(128, cnt - tile_base);
  const int off = wsi[16 + e] + tile_base;
  const int c0 = colblk * 64;      // out-col base

  constexpr int SLOT = 16384;
  __shared__ char lds[3 * SLOT];
  __shared__ int s_rows[128];

  const int t = threadIdx.x;
  if (t < 128) s_rows[t] = rowlist[off + min(t, tile_cnt - 1)];
  __syncthreads();

  // Staging: thread t covers rows/cols (t>>2) and 64+(t>>2), slot chunk t&3.
  // Source chunk = (t&3) ^ ((t>>3)&3) pre-applies read swizzle sigma(r)=(r>>1)&3.
  const int srow = t >> 2;
  const int coff = ((t & 3) ^ ((t >> 3) & 3)) * 16;
  const char* sA0 = (const char*)Hb + (size_t)(s_rows[srow] >> 1) * (KD * 2) + coff;
  const char* sA1 = (const char*)Hb + (size_t)(s_rows[64 + srow] >> 1) * (KD * 2) + coff;
  auto wcol_of = [&](int jc) {   // jc in [0,128): LDS B col -> weight col
    const int wn_s = jc >> 6, r64 = jc & 63;
    const int h_s = r64 >> 4, l_s = r64 & 15;
    return (h_s < 2) ? (c0 + wn_s * 32 + h_s * 16 + l_s)
                     : (OUTN + c0 + wn_s * 32 + (h_s - 2) * 16 + l_s);
  };
  const char* sB0 = (const char*)Wt + ((size_t)e * ND + wcol_of(srow)) * (KD * 2) + coff;
  const char* sB1 = (const char*)Wt + ((size_t)e * ND + wcol_of(64 + srow)) * (KD * 2) + coff;

  const int lane = t & 63, wid = t >> 6;
  const int wm = wid >> 1, wn = wid & 1;
  const int kc = lane >> 4, l15 = lane & 15;

  f32x4 acc[4][4];
  #pragma unroll
  for (int m = 0; m < 4; ++m)
    #pragma unroll
    for (int h = 0; h < 4; ++h)
      acc[m][h] = (f32x4){0.f, 0.f, 0.f, 0.f};

  int aoff[4], boff[4];
  #pragma unroll
  for (int m = 0; m < 4; ++m) {
    const int r = wm * 64 + m * 16 + l15;
    aoff[m] = r * 64 + ((kc ^ ((r >> 1) & 3)) * 16);
  }
  #pragma unroll
  for (int h = 0; h < 4; ++h) {
    const int jc = wn * 64 + h * 16 + l15;
    boff[h] = 8192 + jc * 64 + ((kc ^ ((jc >> 1) & 3)) * 16);
  }

  auto SAB = [&](int h, char* slot) {   // stage K-step h (64B/row): 4 loads
    const int go = h * 64;
    gload16(sA0 + go, slot + t * 16);
    gload16(sA1 + go, slot + 4096 + t * 16);
    gload16(sB0 + go, slot + 8192 + t * 16);
    gload16(sB1 + go, slot + 12288 + t * 16);
  };

  bf16x8 af[4], bfv[4];
  auto LD = [&](const char* cb) {
    #pragma unroll
    for (int m = 0; m < 4; ++m) af[m] = *(const bf16x8*)(cb + aoff[m]);
    #pragma unroll
    for (int h = 0; h < 4; ++h) bfv[h] = *(const bf16x8*)(cb + boff[h]);
  };
  auto MM = [&]() {
    __builtin_amdgcn_s_setprio(1);
    #pragma unroll
    for (int m = 0; m < 4; ++m)
      #pragma unroll
      for (int h = 0; h < 4; ++h)
        acc[m][h] =
            __builtin_amdgcn_mfma_f32_16x16x32_bf16(af[m], bfv[h], acc[m][h], 0, 0, 0);
    __builtin_amdgcn_s_setprio(0);
  };
#define GUARD4 asm volatile("s_waitcnt vmcnt(4)" ::: "memory")
#define GUARD0 asm volatile("s_waitcnt vmcnt(0)" ::: "memory")
#define BAR __builtin_amdgcn_s_barrier()

  // Prologue: stage K-steps 0,1; retire step 0's loads only.
  SAB(0, lds);
  SAB(1, lds + SLOT);
  GUARD4; BAR;

  char* s0 = lds;
  char* s1 = lds + SLOT;
  char* s2 = lds + 2 * SLOT;
  for (int k = 0; k < 30; ++k) {
    SAB(k + 2, s2);      // stage into slot(k-1): readers passed last barrier
    LD(s0);              // 8 ds_read_b128 (conflict-free)
    MM();                // 16 MFMA (lgkm drained by consumption)
    GUARD4; BAR;         // retire step k-1's 4 loads (2 K-steps of slack)
    char* tmp = s0; s0 = s1; s1 = s2; s2 = tmp;
  }
  // k=30: nothing left to stage; retire step 29's loads (slot of step 31).
  LD(s0); MM();
  GUARD0; BAR;
  { char* tmp = s0; s0 = s1; s1 = s2; s2 = tmp; }
  // k=31
  LD(s0); MM();
#undef GUARD4
#undef GUARD0
#undef BAR

  // Fused epilogue: gate = acc[m][h], up = acc[m][h+2], h in {0,1}.
  #pragma unroll
  for (int m = 0; m < 4; ++m) {
    const int rbase = wm * 64 + m * 16 + kc * 4;
    #pragma unroll
    for (int i = 0; i < 4; ++i) {
      const int rl = rbase + i;
      if (rl < tile_cnt) {
        const size_t orow = (size_t)s_rows[rl] * OUTN;
        #pragma unroll
        for (int h = 0; h < 2; ++h) {
          float gg = acc[m][h][i];
          float uu = acc[m][h + 2][i];
          float s = gg / (1.0f + __expf(-gg)) * uu;
          Out[orow + c0 + wn * 32 + h * 16 + l15] = s;
        }
      }
    }
  }
}

extern "C" void kernel_launch(void* const* d_in, const int* in_sizes, int n_in,
                              void* d_out, int out_size, void* d_ws, size_t ws_size,
                              hipStream_t stream) {
  const float* H  = (const float*)d_in[0];
  const float* W  = (const float*)d_in[1];
  const int* ids  = (const int*)d_in[2];
  float* Out      = (float*)d_out;
  char* ws        = (char*)d_ws;
  int* wsi        = (int*)ws;
  int* rowlist    = (int*)(ws + WS_ROWLIST);
  unsigned short* Hb = (unsigned short*)(ws + WS_HB);
  unsigned short* Wt = (unsigned short*)(ws + WS_WT);

  hipMemsetAsync(ws, 0, 1024, stream);
  k_count<<<RFLAT / 512, 256, 0, stream>>>(ids, wsi);
  k_scan<<<1, 64, 0, stream>>>(wsi);
  k_scatter<<<RFLAT / 256, 256, 0, stream>>>(ids, wsi, rowlist);
  k_cvtH<<<2048, 256, 0, stream>>>(H, Hb);
  k_cvtW<<<dim3(ND / 64, KD / 64, NE), 512, 0, stream>>>(W, Wt);
  // rowtiles (128-row) <= 263: 33 slots/XCD x 8 XCDs x 16 colblocks
  k_gemm<<<8 * 33 * 16, 256, 0, stream>>>(Hb, Wt, wsi, rowlist, Out);
}